// Round 9
// baseline (48.086 us; speedup 1.0000x reference)
//
#include <hip/hip_runtime.h>
#include <hip/hip_bf16.h>
#include <math.h>

#define DD 128
#define CC 100
#define NPAD 112          // 7 tiles of 16
#define NT 7
#define MARGIN_F 0.5f
#define EPS_F 1e-6f
#define RW 16             // rows per wave per chunk
#define CH 4              // chunks per wave (software pipeline depth)
#define BROWS 256         // rows per block = 4 waves * RW * CH
#define NFRAG (NT * 4)    // 28 B-fragments

typedef __attribute__((ext_vector_type(8))) short bf16x8;
typedef __attribute__((ext_vector_type(4))) float f32x4;

__device__ __forceinline__ float fsqrt_f(float x) { return __builtin_amdgcn_sqrtf(x); }
__device__ __forceinline__ float frcp_f(float x)  { return __builtin_amdgcn_rcpf(x); }

__device__ __forceinline__ short f2bf(float x) {
    __hip_bfloat16 h = __float2bfloat16(x);
    return *reinterpret_cast<short*>(&h);
}

// Single fused kernel. Each block redundantly preps the prototypes (51 KB,
// L2/L3-broadcast across blocks) into LDS, then runs the 4-chunk pipelined
// main loop. vmcnt carries ONLY the 9 prefetch loads per chunk in the loop.
// d_pos via 4-MFMA gather (bitwise-equal to the label column of the main
// MFMA); each row's hinge over the label column contributes exactly MARGIN,
// compensated by subtracting MARGIN/16 per lane (each row is replicated
// across the 16 lanes sharing g — round 8 subtracted the full MARGIN in all
// 64 lanes, a 16x over-subtraction, absmax 0.076 = 15*MARGIN/(C-1)).
// Hinge via min-trick: sum relu(hb-dist) = 7*hb - sum min(dist, hb) per lane;
// pad cols (cj=1e9 -> dist~3e4) and OOR rows (hb=0) contribute exactly 0.
__global__ __launch_bounds__(256) void proto_main_kernel(
        const float* __restrict__ feat,
        const float* __restrict__ prot,
        const int* __restrict__ labels,
        float* __restrict__ out,
        int Bn, float scale) {
    const int tid = threadIdx.x;
    const int lane = tid & 63;
    const int w = tid >> 6;
    const int g = lane >> 4, m = lane & 15;
    const long blkbase = (long)blockIdx.x * BROWS;

    __shared__ bf16x8 pnl[NFRAG * 64];   // 28 KB
    __shared__ float cjs[NPAD];          // 448 B
    __shared__ float invs[CC];           // 400 B
    __shared__ float red[4];

    // issue chunk-0 feature+label loads FIRST (oldest on vmcnt; they
    // complete for free under the prep phase below)
    float4 va[8];
    int lab;
    {
        long row = blkbase + w * RW + m;
        long rs = row < Bn ? row : (long)(Bn - 1);
        lab = labels[rs];
        const float4* fp = (const float4*)(feat + rs * DD);
#pragma unroll
        for (int kk = 0; kk < 4; ++kk) {
            va[kk * 2]     = fp[kk * 8 + g * 2];
            va[kk * 2 + 1] = fp[kk * 8 + g * 2 + 1];
        }
    }

    // ---- fused prototype prep: norms (2 threads / proto) ----
    if (tid < 2 * CC) {
        int j = tid >> 1, h = tid & 1;
        const float4* pr = (const float4*)(prot + j * DD + h * 64);
        float ss = 0.f, s1 = 0.f;
#pragma unroll
        for (int e = 0; e < 16; ++e) {
            float4 v = pr[e];
            ss += v.x * v.x + v.y * v.y + v.z * v.z + v.w * v.w;
            s1 += v.x + v.y + v.z + v.w;
        }
        ss += __shfl_xor(ss, 1);   // partner lane^1 holds the other half-row
        s1 += __shfl_xor(s1, 1);
        float inv = 1.0f / fmaxf(sqrtf(ss), 1e-12f);
        if (h == 0) {
            invs[j] = inv;
            cjs[j] = ss * inv * inv - 2.0f * EPS_F * (s1 * inv);
        }
    }
    if (tid >= CC && tid < NPAD) cjs[tid] = 1e9f;
    __syncthreads();

    // ---- fused prototype prep: B-fragment build (7 frag-slots / thread) ----
    // frag f = t*4+kk; lane l holds n = (f>>2)*16+(l&15), k = kk*32+(l>>4)*8+q
#pragma unroll
    for (int i = 0; i < NFRAG * 64 / 256; ++i) {
        int idx = i * 256 + tid;
        int f = idx >> 6, l = idx & 63;
        int n = (f >> 2) * 16 + (l & 15);
        int kk = f & 3, k0 = kk * 32 + (l >> 4) * 8;
        bf16x8 o;
        if (n < CC) {
            float inv = invs[n];
            const float4* pr = (const float4*)(prot + n * DD + k0);
            float4 a = pr[0], b = pr[1];
            o[0] = f2bf(a.x * inv); o[1] = f2bf(a.y * inv);
            o[2] = f2bf(a.z * inv); o[3] = f2bf(a.w * inv);
            o[4] = f2bf(b.x * inv); o[5] = f2bf(b.y * inv);
            o[6] = f2bf(b.z * inv); o[7] = f2bf(b.w * inv);
        } else {
#pragma unroll
            for (int q = 0; q < 8; ++q) o[q] = 0;
        }
        pnl[idx] = o;
    }
    __syncthreads();   // prep done; chunk-0 loads long since landed

    // loop-invariant: my 7 columns' cj (LDS)
    float cjr[NT];
#pragma unroll
    for (int t = 0; t < NT; ++t) cjr[t] = cjs[t * 16 + m];

    float hsum = 0.f;

#pragma unroll
    for (int c = 0; c < CH; ++c) {
        // row stats from raw floats (uses va of chunk c)
        float ss = 0.f, s1 = 0.f;
#pragma unroll
        for (int q = 0; q < 8; ++q) {
            float4 v = va[q];
            ss += v.x * v.x + v.y * v.y + v.z * v.z + v.w * v.w;
            s1 += v.x + v.y + v.z + v.w;
        }
        ss += __shfl_xor(ss, 16); ss += __shfl_xor(ss, 32);
        s1 += __shfl_xor(s1, 16); s1 += __shfl_xor(s1, 32);
        float inv = frcp_f(fmaxf(fsqrt_f(ss), 1e-12f));
        float cf = ss * inv * inv + 2.f * EPS_F * (s1 * inv)
                 + (float)DD * (EPS_F * EPS_F);
        float m2i = -2.f * inv;
        int labc = lab;

        // raw floats -> bf16 A fragments (frees va for the prefetch)
        bf16x8 afr[4];
#pragma unroll
        for (int kk = 0; kk < 4; ++kk) {
            float4 a = va[kk * 2], b = va[kk * 2 + 1];
            union { bf16x8 v; __hip_bfloat162 h[4]; } u;
            u.h[0] = __float22bfloat162_rn(make_float2(a.x, a.y));
            u.h[1] = __float22bfloat162_rn(make_float2(a.z, a.w));
            u.h[2] = __float22bfloat162_rn(make_float2(b.x, b.y));
            u.h[3] = __float22bfloat162_rn(make_float2(b.z, b.w));
            afr[kk] = u.v;
        }

        // prefetch next chunk's label + features (ONLY vmcnt ops in the loop)
        if (c + 1 < CH) {
            long nrow = blkbase + (c + 1) * 64 + w * RW + m;
            long nrs = nrow < Bn ? nrow : (long)(Bn - 1);
            lab = labels[nrs];
            const float4* fp = (const float4*)(feat + nrs * DD);
#pragma unroll
            for (int kk = 0; kk < 4; ++kk) {
                va[kk * 2]     = fp[kk * 8 + g * 2];
                va[kk * 2 + 1] = fp[kk * 8 + g * 2 + 1];
            }
        }

        // per-row stats for my output rows q=g*4+r (held by lane q)
        float cf_r[4], m2i_r[4];
        int lab_r[4];
#pragma unroll
        for (int r = 0; r < 4; ++r) {
            int addr = (g * 4 + r) << 2;
            cf_r[r]  = __int_as_float(__builtin_amdgcn_ds_bpermute(addr, __float_as_int(cf)));
            m2i_r[r] = __int_as_float(__builtin_amdgcn_ds_bpermute(addr, __float_as_int(m2i)));
            lab_r[r] = __builtin_amdgcn_ds_bpermute(addr, labc);
        }
        // cj of each row's label prototype
        float cjl_r[4];
#pragma unroll
        for (int r = 0; r < 4; ++r) cjl_r[r] = cjs[lab_r[r]];

        // d_pos dots via gathered-B MFMA: col q of B = proto label[row q]
        f32x4 accpos = (f32x4)0.f;
        {
            int lanehi = lane & 48;
            int fbase = (labc >> 4) << 2;
            int lsub  = lanehi + (labc & 15);
#pragma unroll
            for (int kk = 0; kk < 4; ++kk) {
                bf16x8 bp = pnl[(fbase + kk) * 64 + lsub];
                accpos = __builtin_amdgcn_mfma_f32_16x16x32_bf16(
                    afr[kk], bp, accpos, 0, 0, 0);
            }
        }
        // diagonal D[q][q]: holder lane = (q>>2)*16+q holds it in reg q&3
        float a01 = (lane & 1) ? accpos[1] : accpos[0];
        float a23 = (lane & 1) ? accpos[3] : accpos[2];
        float vsrc = (lane & 2) ? a23 : a01;
        float hb[4];
        {
            int hl = (lane >> 4) * 20;   // holder lane for q=g*4+r is 20g+r
#pragma unroll
            for (int r = 0; r < 4; ++r) {
                float dotp = __int_as_float(
                    __builtin_amdgcn_ds_bpermute((hl + r) << 2, __float_as_int(vsrc)));
                float d2p = fmaf(dotp, m2i_r[r], cf_r[r]) + cjl_r[r];
                float dpd = fsqrt_f(fmaxf(d2p, 1e-12f));
                long rr = blkbase + c * 64 + w * RW + g * 4 + r;
                bool valid = rr < (long)Bn;
                hb[r] = valid ? (dpd + MARGIN_F) : 0.f;
                // label col contributes exactly MARGIN per ROW; each row is
                // replicated across 16 lanes -> subtract MARGIN/16 per lane
                // (exactly representable: 16 * 0.03125 = 0.5 exact)
                hsum -= valid ? (MARGIN_F * (1.0f / 16.0f)) : 0.f;
            }
        }

        // main MFMA: [16 rows] x [112 cols]; B operands via ds_read_b128
        f32x4 acc[NT];
#pragma unroll
        for (int t = 0; t < NT; ++t) acc[t] = (f32x4)0.f;
#pragma unroll
        for (int t = 0; t < NT; ++t) {
            bf16x8 bfr[4];
#pragma unroll
            for (int kk = 0; kk < 4; ++kk) bfr[kk] = pnl[(t * 4 + kk) * 64 + lane];
#pragma unroll
            for (int kk = 0; kk < 4; ++kk)
                acc[t] = __builtin_amdgcn_mfma_f32_16x16x32_bf16(
                    afr[kk], bfr[kk], acc[t], 0, 0, 0);
        }

        // epilogue: 5 instr/elem {fma, add, sqrt, min, add}
        float ms0 = 0.f, ms1 = 0.f, ms2 = 0.f, ms3 = 0.f;
#pragma unroll
        for (int t = 0; t < NT; ++t) {
            float e0 = fmaf(acc[t][0], m2i_r[0], cf_r[0]);
            float e1 = fmaf(acc[t][1], m2i_r[1], cf_r[1]);
            float e2 = fmaf(acc[t][2], m2i_r[2], cf_r[2]);
            float e3 = fmaf(acc[t][3], m2i_r[3], cf_r[3]);
            ms0 += fminf(fsqrt_f(e0 + cjr[t]), hb[0]);
            ms1 += fminf(fsqrt_f(e1 + cjr[t]), hb[1]);
            ms2 += fminf(fsqrt_f(e2 + cjr[t]), hb[2]);
            ms3 += fminf(fsqrt_f(e3 + cjr[t]), hb[3]);
        }
        hsum += fmaf((float)NT, hb[0], -ms0);
        hsum += fmaf((float)NT, hb[1], -ms1);
        hsum += fmaf((float)NT, hb[2], -ms2);
        hsum += fmaf((float)NT, hb[3], -ms3);
    }

    // wave reduce + 1 barrier + 1 atomic per block
#pragma unroll
    for (int off = 32; off > 0; off >>= 1) hsum += __shfl_xor(hsum, off);
    if (lane == 0) red[w] = hsum;
    __syncthreads();
    if (threadIdx.x == 0)
        atomicAdd(out, (red[0] + red[1] + red[2] + red[3]) * scale);
}

extern "C" void kernel_launch(void* const* d_in, const int* in_sizes, int n_in,
                              void* d_out, int out_size, void* d_ws, size_t ws_size,
                              hipStream_t stream) {
    const float* feat   = (const float*)d_in[0];
    const float* prot   = (const float*)d_in[1];
    const int*   labels = (const int*)d_in[2];
    float* out = (float*)d_out;
    int Bn = in_sizes[0] / DD;

    hipMemsetAsync(d_out, 0, sizeof(float), stream);

    int blocks = (Bn + BROWS - 1) / BROWS;
    float scale = 1.0f / ((float)Bn * (float)(CC - 1));
    proto_main_kernel<<<blocks, 256, 0, stream>>>(feat, prot, labels, out, Bn, scale);
}

// Round 10
// 41.806 us; speedup vs baseline: 1.1502x; 1.1502x over previous
//
#include <hip/hip_runtime.h>
#include <hip/hip_bf16.h>
#include <math.h>

#define DD 128
#define CC 100
#define NPAD 112          // 7 tiles of 16
#define NT 7
#define MARGIN_F 0.5f
#define EPS_F 1e-6f
#define RW 16             // rows per wave per chunk
#define CH 4              // chunks per wave (software pipeline depth)
#define BROWS 256         // rows per block = 4 waves * RW * CH
#define NFRAG (NT * 4)    // 28 B-fragments

typedef __attribute__((ext_vector_type(8))) short bf16x8;
typedef __attribute__((ext_vector_type(4))) float f32x4;

__device__ __forceinline__ float fsqrt_f(float x) { return __builtin_amdgcn_sqrtf(x); }
__device__ __forceinline__ float frcp_f(float x)  { return __builtin_amdgcn_rcpf(x); }

__device__ __forceinline__ short f2bf(float x) {
    __hip_bfloat16 h = __float2bfloat16(x);
    return *reinterpret_cast<short*>(&h);
}

// prep: block j normalizes prototype j, emits cj[j] and B-fragment-major
// bf16 slices. j>=100: zero frags, cj=1e9 (pad kills hinge via min-trick).
// Block 0 initializes out to -MARGIN/(C-1): the label column of the main
// MFMA contributes exactly MARGIN per row (the d_pos gather-MFMA is
// bitwise-identical to it), so one global subtraction compensates exactly.
__global__ void prep_kernel(const float* __restrict__ p,
                            float* __restrict__ cj,
                            bf16x8* __restrict__ pnb,
                            float* __restrict__ out) {
    int j = blockIdx.x, tid = threadIdx.x;
    if (j == 0 && tid == 0) out[0] = -MARGIN_F / (float)(CC - 1);

    float inv = 0.0f;
    if (j < CC) {
        float a = p[j * DD + tid];
        float b = p[j * DD + tid + 64];
        float ss = a * a + b * b;
        float s1 = a + b;
#pragma unroll
        for (int off = 1; off < 64; off <<= 1) {
            ss += __shfl_xor(ss, off);
            s1 += __shfl_xor(s1, off);
        }
        inv = 1.0f / fmaxf(sqrtf(ss), 1e-12f);
        if (tid == 0) cj[j] = ss * inv * inv - 2.0f * EPS_F * (s1 * inv);
    } else {
        if (tid == 0) cj[j] = 1e9f;
    }

    if (tid < 16) {
        int kk = tid >> 2, g = tid & 3;
        int frag = (j >> 4) * 4 + kk;
        int lane = g * 16 + (j & 15);
        bf16x8 o;
        if (j < CC) {
            const float* row = p + j * DD + kk * 32 + g * 8;
#pragma unroll
            for (int q = 0; q < 8; ++q) o[q] = f2bf(row[q] * inv);
        } else {
#pragma unroll
            for (int q = 0; q < 8; ++q) o[q] = 0;
        }
        pnb[frag * 64 + lane] = o;
    }
}

// main: 4 waves/block, 16 rows/wave/chunk, 4 chunks software-pipelined.
// vmcnt carries ONLY the 9 prefetch loads per chunk in the loop (round-6
// invariant); B fragments live in LDS (lgkmcnt domain).
// TAIL=false (Bn % BROWS == 0, the actual shape): no row clamps, no valid
// masks — all rows real. d_pos via 4-MFMA gather; hinge via min-trick:
// sum relu(hb-dist) = 7*hb - sum min(dist, hb) per lane; pad cols
// (cj=1e9 -> dist~3e4 -> min=hb) contribute exactly 0.
template <bool TAIL>
__global__ __launch_bounds__(256) void proto_main_kernel(
        const float* __restrict__ feat,
        const bf16x8* __restrict__ pnb,
        const float* __restrict__ cj,
        const int* __restrict__ labels,
        float* __restrict__ out,
        int Bn, float scale) {
    const int lane = threadIdx.x & 63;
    const int w = threadIdx.x >> 6;
    const int g = lane >> 4, m = lane & 15;
    const long blkbase = (long)blockIdx.x * BROWS;

    __shared__ bf16x8 pnl[NFRAG * 64];   // 28 KB
    __shared__ float cjs[NPAD];          // 448 B
    __shared__ float red[4];

    // loop-invariant: my 7 columns' cj
    float cjr[NT];
#pragma unroll
    for (int t = 0; t < NT; ++t) cjr[t] = cj[t * 16 + m];

    // issue chunk-0 feature+label loads FIRST (oldest on vmcnt; they land
    // under the LDS staging below)
    float4 va[8];
    int lab;
    {
        long row = blkbase + w * RW + m;
        long rs = (!TAIL || row < Bn) ? row : (long)(Bn - 1);
        lab = labels[rs];
        const float4* fp = (const float4*)(feat + rs * DD);
#pragma unroll
        for (int kk = 0; kk < 4; ++kk) {
            va[kk * 2]     = fp[kk * 8 + g * 2];
            va[kk * 2 + 1] = fp[kk * 8 + g * 2 + 1];
        }
    }

    // stage B fragments + cj table into LDS (once per block)
#pragma unroll
    for (int i = 0; i < NFRAG * 64 / 256; ++i)
        pnl[i * 256 + threadIdx.x] = pnb[i * 256 + threadIdx.x];
    if (threadIdx.x < NPAD) cjs[threadIdx.x] = cj[threadIdx.x];
    __syncthreads();   // drains staging (and chunk-0 loads with it)

    float hsum = 0.f;

#pragma unroll
    for (int c = 0; c < CH; ++c) {
        int labc = lab;

        // row-stat sums from raw floats (uses va of chunk c)
        float ss = 0.f, s1 = 0.f;
#pragma unroll
        for (int q = 0; q < 8; ++q) {
            float4 v = va[q];
            ss += v.x * v.x + v.y * v.y + v.z * v.z + v.w * v.w;
            s1 += v.x + v.y + v.z + v.w;
        }

        // raw floats -> bf16 A fragments (frees va for the prefetch)
        bf16x8 afr[4];
#pragma unroll
        for (int kk = 0; kk < 4; ++kk) {
            float4 a = va[kk * 2], b = va[kk * 2 + 1];
            union { bf16x8 v; __hip_bfloat162 h[4]; } u;
            u.h[0] = __float22bfloat162_rn(make_float2(a.x, a.y));
            u.h[1] = __float22bfloat162_rn(make_float2(a.z, a.w));
            u.h[2] = __float22bfloat162_rn(make_float2(b.x, b.y));
            u.h[3] = __float22bfloat162_rn(make_float2(b.z, b.w));
            afr[kk] = u.v;
        }

        // prefetch next chunk's label + features ASAP (ONLY vmcnt ops in
        // the loop; issued before the shuffle/sqrt chain to lengthen the
        // latency shadow)
        if (c + 1 < CH) {
            long nrow = blkbase + (c + 1) * 64 + w * RW + m;
            long nrs = (!TAIL || nrow < Bn) ? nrow : (long)(Bn - 1);
            lab = labels[nrs];
            const float4* fp = (const float4*)(feat + nrs * DD);
#pragma unroll
            for (int kk = 0; kk < 4; ++kk) {
                va[kk * 2]     = fp[kk * 8 + g * 2];
                va[kk * 2 + 1] = fp[kk * 8 + g * 2 + 1];
            }
        }

        // finish row stats (register/LDS-only from here to end of chunk)
        ss += __shfl_xor(ss, 16); ss += __shfl_xor(ss, 32);
        s1 += __shfl_xor(s1, 16); s1 += __shfl_xor(s1, 32);
        float inv = frcp_f(fmaxf(fsqrt_f(ss), 1e-12f));
        float cf = ss * inv * inv + 2.f * EPS_F * (s1 * inv)
                 + (float)DD * (EPS_F * EPS_F);
        float m2i = -2.f * inv;

        __builtin_amdgcn_s_setprio(1);

        // per-row stats for my output rows q=g*4+r (held by lane q)
        float cf_r[4], m2i_r[4];
        int lab_r[4];
#pragma unroll
        for (int r = 0; r < 4; ++r) {
            int addr = (g * 4 + r) << 2;
            cf_r[r]  = __int_as_float(__builtin_amdgcn_ds_bpermute(addr, __float_as_int(cf)));
            m2i_r[r] = __int_as_float(__builtin_amdgcn_ds_bpermute(addr, __float_as_int(m2i)));
            lab_r[r] = __builtin_amdgcn_ds_bpermute(addr, labc);
        }
        // cj of each row's label prototype
        float cjl_r[4];
#pragma unroll
        for (int r = 0; r < 4; ++r) cjl_r[r] = cjs[lab_r[r]];

        // d_pos dots via gathered-B MFMA: col q of B = proto label[row q]
        f32x4 accpos = (f32x4)0.f;
        {
            int lanehi = lane & 48;
            int fbase = (labc >> 4) << 2;
            int lsub  = lanehi + (labc & 15);
#pragma unroll
            for (int kk = 0; kk < 4; ++kk) {
                bf16x8 bp = pnl[(fbase + kk) * 64 + lsub];
                accpos = __builtin_amdgcn_mfma_f32_16x16x32_bf16(
                    afr[kk], bp, accpos, 0, 0, 0);
            }
        }
        // diagonal D[q][q]: holder lane = (q>>2)*16+q holds it in reg q&3
        float a01 = (lane & 1) ? accpos[1] : accpos[0];
        float a23 = (lane & 1) ? accpos[3] : accpos[2];
        float vsrc = (lane & 2) ? a23 : a01;
        float hb[4];
        {
            int hl = (lane >> 4) * 20;   // holder lane for q=g*4+r is 20g+r
#pragma unroll
            for (int r = 0; r < 4; ++r) {
                float dotp = __int_as_float(
                    __builtin_amdgcn_ds_bpermute((hl + r) << 2, __float_as_int(vsrc)));
                float d2p = fmaf(dotp, m2i_r[r], cf_r[r]) + cjl_r[r];
                float dpd = fsqrt_f(fmaxf(d2p, 1e-12f));
                if (TAIL) {
                    long rr = blkbase + c * 64 + w * RW + g * 4 + r;
                    hb[r] = (rr < (long)Bn) ? (dpd + MARGIN_F) : 0.f;
                } else {
                    hb[r] = dpd + MARGIN_F;
                }
            }
        }

        // main MFMA: [16 rows] x [112 cols]; B operands via ds_read_b128
        f32x4 acc[NT];
#pragma unroll
        for (int t = 0; t < NT; ++t) acc[t] = (f32x4)0.f;
#pragma unroll
        for (int t = 0; t < NT; ++t) {
            bf16x8 bfr[4];
#pragma unroll
            for (int kk = 0; kk < 4; ++kk) bfr[kk] = pnl[(t * 4 + kk) * 64 + lane];
#pragma unroll
            for (int kk = 0; kk < 4; ++kk)
                acc[t] = __builtin_amdgcn_mfma_f32_16x16x32_bf16(
                    afr[kk], bfr[kk], acc[t], 0, 0, 0);
        }

        // epilogue: 5 instr/elem {fma, add, sqrt, min, add}
        float ms0 = 0.f, ms1 = 0.f, ms2 = 0.f, ms3 = 0.f;
#pragma unroll
        for (int t = 0; t < NT; ++t) {
            float e0 = fmaf(acc[t][0], m2i_r[0], cf_r[0]);
            float e1 = fmaf(acc[t][1], m2i_r[1], cf_r[1]);
            float e2 = fmaf(acc[t][2], m2i_r[2], cf_r[2]);
            float e3 = fmaf(acc[t][3], m2i_r[3], cf_r[3]);
            ms0 += fminf(fsqrt_f(e0 + cjr[t]), hb[0]);
            ms1 += fminf(fsqrt_f(e1 + cjr[t]), hb[1]);
            ms2 += fminf(fsqrt_f(e2 + cjr[t]), hb[2]);
            ms3 += fminf(fsqrt_f(e3 + cjr[t]), hb[3]);
        }
        hsum += fmaf((float)NT, hb[0], -ms0);
        hsum += fmaf((float)NT, hb[1], -ms1);
        hsum += fmaf((float)NT, hb[2], -ms2);
        hsum += fmaf((float)NT, hb[3], -ms3);

        __builtin_amdgcn_s_setprio(0);
    }

    // wave reduce + 1 barrier + 1 atomic per block
#pragma unroll
    for (int off = 32; off > 0; off >>= 1) hsum += __shfl_xor(hsum, off);
    if (lane == 0) red[w] = hsum;
    __syncthreads();
    if (threadIdx.x == 0)
        atomicAdd(out, (red[0] + red[1] + red[2] + red[3]) * scale);
}

extern "C" void kernel_launch(void* const* d_in, const int* in_sizes, int n_in,
                              void* d_out, int out_size, void* d_ws, size_t ws_size,
                              hipStream_t stream) {
    const float* feat   = (const float*)d_in[0];
    const float* prot   = (const float*)d_in[1];
    const int*   labels = (const int*)d_in[2];
    float* out = (float*)d_out;
    int Bn = in_sizes[0] / DD;

    bf16x8* pnb = (bf16x8*)d_ws;                       // 28*64*16B = 28672 B
    float* cjw  = (float*)((char*)d_ws + 28 * 64 * 16);

    prep_kernel<<<NPAD, 64, 0, stream>>>(prot, cjw, pnb, out);

    int blocks = (Bn + BROWS - 1) / BROWS;
    float scale = 1.0f / ((float)Bn * (float)(CC - 1));
    if (Bn % BROWS == 0)
        proto_main_kernel<false><<<blocks, 256, 0, stream>>>(feat, pnb, cjw, labels, out, Bn, scale);
    else
        proto_main_kernel<true><<<blocks, 256, 0, stream>>>(feat, pnb, cjw, labels, out, Bn, scale);
}

// Round 11
// 40.372 us; speedup vs baseline: 1.1911x; 1.0355x over previous
//
#include <hip/hip_runtime.h>
#include <hip/hip_bf16.h>
#include <math.h>

#define DD 128
#define CC 100
#define NPAD 112          // 7 tiles of 16
#define NT 7
#define MARGIN_F 0.5f
#define EPS_F 1e-6f
#define RW 16             // rows per wave per chunk
#define CH 4              // chunks per wave (software pipeline depth)
#define BROWS 256         // rows per block = 4 waves * RW * CH
#define NFRAG (NT * 4)    // 28 B-fragments

typedef __attribute__((ext_vector_type(8))) short bf16x8;
typedef __attribute__((ext_vector_type(4))) float f32x4;

__device__ __forceinline__ float fsqrt_f(float x) { return __builtin_amdgcn_sqrtf(x); }
__device__ __forceinline__ float frcp_f(float x)  { return __builtin_amdgcn_rcpf(x); }

__device__ __forceinline__ short f2bf(float x) {
    __hip_bfloat16 h = __float2bfloat16(x);
    return *reinterpret_cast<short*>(&h);
}

// prep: block j normalizes prototype j, emits cj[j] and B-fragment-major
// bf16 slices. j>=100: zero frags, cj=1e9 (pad kills hinge via min-trick).
// Block 0 initializes out to -MARGIN/(C-1): the label column of the main
// MFMA contributes exactly MARGIN per row (the d_pos gather-MFMA is
// bitwise-identical to it), so one global subtraction compensates exactly.
__global__ void prep_kernel(const float* __restrict__ p,
                            float* __restrict__ cj,
                            bf16x8* __restrict__ pnb,
                            float* __restrict__ out) {
    int j = blockIdx.x, tid = threadIdx.x;
    if (j == 0 && tid == 0) out[0] = -MARGIN_F / (float)(CC - 1);

    float inv = 0.0f;
    if (j < CC) {
        float a = p[j * DD + tid];
        float b = p[j * DD + tid + 64];
        float ss = a * a + b * b;
        float s1 = a + b;
#pragma unroll
        for (int off = 1; off < 64; off <<= 1) {
            ss += __shfl_xor(ss, off);
            s1 += __shfl_xor(s1, off);
        }
        inv = 1.0f / fmaxf(sqrtf(ss), 1e-12f);
        if (tid == 0) cj[j] = ss * inv * inv - 2.0f * EPS_F * (s1 * inv);
    } else {
        if (tid == 0) cj[j] = 1e9f;
    }

    if (tid < 16) {
        int kk = tid >> 2, g = tid & 3;
        int frag = (j >> 4) * 4 + kk;
        int lane = g * 16 + (j & 15);
        bf16x8 o;
        if (j < CC) {
            const float* row = p + j * DD + kk * 32 + g * 8;
#pragma unroll
            for (int q = 0; q < 8; ++q) o[q] = f2bf(row[q] * inv);
        } else {
#pragma unroll
            for (int q = 0; q < 8; ++q) o[q] = 0;
        }
        pnb[frag * 64 + lane] = o;
    }
}

// main: 4 waves/block, 16 rows/wave/chunk, 4 chunks software-pipelined.
// vmcnt carries ONLY the 9 prefetch loads per chunk in the loop (round-6
// invariant); B fragments live in LDS (lgkmcnt domain).
// NO s_setprio: with 4 symmetric waves/SIMD it starves other waves'
// prefetch-issue (m190 GEMM-negative mechanism) — R10 measured +1.8us.
// TAIL=false (Bn % BROWS == 0): no row clamps or valid masks.
// d_pos via 4-MFMA gather; hinge via min-trick:
// sum relu(hb-dist) = 7*hb - sum min(dist, hb) per lane; pad cols
// (cj=1e9 -> dist~3e4 -> min=hb) contribute exactly 0.
template <bool TAIL>
__global__ __launch_bounds__(256) void proto_main_kernel(
        const float* __restrict__ feat,
        const bf16x8* __restrict__ pnb,
        const float* __restrict__ cj,
        const int* __restrict__ labels,
        float* __restrict__ out,
        int Bn, float scale) {
    const int lane = threadIdx.x & 63;
    const int w = threadIdx.x >> 6;
    const int g = lane >> 4, m = lane & 15;
    const long blkbase = (long)blockIdx.x * BROWS;

    __shared__ bf16x8 pnl[NFRAG * 64];   // 28 KB
    __shared__ float cjs[NPAD];          // 448 B
    __shared__ float red[4];

    // loop-invariant: my 7 columns' cj
    float cjr[NT];
#pragma unroll
    for (int t = 0; t < NT; ++t) cjr[t] = cj[t * 16 + m];

    // issue chunk-0 feature+label loads FIRST (oldest on vmcnt; they land
    // under the LDS staging below)
    float4 va[8];
    int lab;
    {
        long row = blkbase + w * RW + m;
        long rs = (!TAIL || row < Bn) ? row : (long)(Bn - 1);
        lab = labels[rs];
        const float4* fp = (const float4*)(feat + rs * DD);
#pragma unroll
        for (int kk = 0; kk < 4; ++kk) {
            va[kk * 2]     = fp[kk * 8 + g * 2];
            va[kk * 2 + 1] = fp[kk * 8 + g * 2 + 1];
        }
    }

    // stage B fragments + cj table into LDS (once per block)
#pragma unroll
    for (int i = 0; i < NFRAG * 64 / 256; ++i)
        pnl[i * 256 + threadIdx.x] = pnb[i * 256 + threadIdx.x];
    if (threadIdx.x < NPAD) cjs[threadIdx.x] = cj[threadIdx.x];
    __syncthreads();   // drains staging (and chunk-0 loads with it)

    float hsum = 0.f;

#pragma unroll
    for (int c = 0; c < CH; ++c) {
        int labc = lab;

        // row-stat sums from raw floats (uses va of chunk c)
        float ss = 0.f, s1 = 0.f;
#pragma unroll
        for (int q = 0; q < 8; ++q) {
            float4 v = va[q];
            ss += v.x * v.x + v.y * v.y + v.z * v.z + v.w * v.w;
            s1 += v.x + v.y + v.z + v.w;
        }

        // raw floats -> bf16 A fragments (frees va for the prefetch)
        bf16x8 afr[4];
#pragma unroll
        for (int kk = 0; kk < 4; ++kk) {
            float4 a = va[kk * 2], b = va[kk * 2 + 1];
            union { bf16x8 v; __hip_bfloat162 h[4]; } u;
            u.h[0] = __float22bfloat162_rn(make_float2(a.x, a.y));
            u.h[1] = __float22bfloat162_rn(make_float2(a.z, a.w));
            u.h[2] = __float22bfloat162_rn(make_float2(b.x, b.y));
            u.h[3] = __float22bfloat162_rn(make_float2(b.z, b.w));
            afr[kk] = u.v;
        }

        // prefetch next chunk's label + features ASAP (ONLY vmcnt ops in
        // the loop; issued before the shuffle/sqrt chain to lengthen the
        // latency shadow)
        if (c + 1 < CH) {
            long nrow = blkbase + (c + 1) * 64 + w * RW + m;
            long nrs = (!TAIL || nrow < Bn) ? nrow : (long)(Bn - 1);
            lab = labels[nrs];
            const float4* fp = (const float4*)(feat + nrs * DD);
#pragma unroll
            for (int kk = 0; kk < 4; ++kk) {
                va[kk * 2]     = fp[kk * 8 + g * 2];
                va[kk * 2 + 1] = fp[kk * 8 + g * 2 + 1];
            }
        }

        // finish row stats (register/LDS-only from here to end of chunk)
        ss += __shfl_xor(ss, 16); ss += __shfl_xor(ss, 32);
        s1 += __shfl_xor(s1, 16); s1 += __shfl_xor(s1, 32);
        float inv = frcp_f(fmaxf(fsqrt_f(ss), 1e-12f));
        float cf = ss * inv * inv + 2.f * EPS_F * (s1 * inv)
                 + (float)DD * (EPS_F * EPS_F);
        float m2i = -2.f * inv;

        // per-row stats for my output rows q=g*4+r (held by lane q)
        float cf_r[4], m2i_r[4];
        int lab_r[4];
#pragma unroll
        for (int r = 0; r < 4; ++r) {
            int addr = (g * 4 + r) << 2;
            cf_r[r]  = __int_as_float(__builtin_amdgcn_ds_bpermute(addr, __float_as_int(cf)));
            m2i_r[r] = __int_as_float(__builtin_amdgcn_ds_bpermute(addr, __float_as_int(m2i)));
            lab_r[r] = __builtin_amdgcn_ds_bpermute(addr, labc);
        }
        // cj of each row's label prototype
        float cjl_r[4];
#pragma unroll
        for (int r = 0; r < 4; ++r) cjl_r[r] = cjs[lab_r[r]];

        // d_pos dots via gathered-B MFMA: col q of B = proto label[row q]
        f32x4 accpos = (f32x4)0.f;
        {
            int lanehi = lane & 48;
            int fbase = (labc >> 4) << 2;
            int lsub  = lanehi + (labc & 15);
#pragma unroll
            for (int kk = 0; kk < 4; ++kk) {
                bf16x8 bp = pnl[(fbase + kk) * 64 + lsub];
                accpos = __builtin_amdgcn_mfma_f32_16x16x32_bf16(
                    afr[kk], bp, accpos, 0, 0, 0);
            }
        }
        // diagonal D[q][q]: holder lane = (q>>2)*16+q holds it in reg q&3
        float a01 = (lane & 1) ? accpos[1] : accpos[0];
        float a23 = (lane & 1) ? accpos[3] : accpos[2];
        float vsrc = (lane & 2) ? a23 : a01;
        float hb[4];
        {
            int hl = (lane >> 4) * 20;   // holder lane for q=g*4+r is 20g+r
#pragma unroll
            for (int r = 0; r < 4; ++r) {
                float dotp = __int_as_float(
                    __builtin_amdgcn_ds_bpermute((hl + r) << 2, __float_as_int(vsrc)));
                float d2p = fmaf(dotp, m2i_r[r], cf_r[r]) + cjl_r[r];
                float dpd = fsqrt_f(fmaxf(d2p, 1e-12f));
                if (TAIL) {
                    long rr = blkbase + c * 64 + w * RW + g * 4 + r;
                    hb[r] = (rr < (long)Bn) ? (dpd + MARGIN_F) : 0.f;
                } else {
                    hb[r] = dpd + MARGIN_F;
                }
            }
        }

        // main MFMA: [16 rows] x [112 cols]; B operands via ds_read_b128
        f32x4 acc[NT];
#pragma unroll
        for (int t = 0; t < NT; ++t) acc[t] = (f32x4)0.f;
#pragma unroll
        for (int t = 0; t < NT; ++t) {
            bf16x8 bfr[4];
#pragma unroll
            for (int kk = 0; kk < 4; ++kk) bfr[kk] = pnl[(t * 4 + kk) * 64 + lane];
#pragma unroll
            for (int kk = 0; kk < 4; ++kk)
                acc[t] = __builtin_amdgcn_mfma_f32_16x16x32_bf16(
                    afr[kk], bfr[kk], acc[t], 0, 0, 0);
        }

        // epilogue: 5 instr/elem {fma, add, sqrt, min, add}
        float ms0 = 0.f, ms1 = 0.f, ms2 = 0.f, ms3 = 0.f;
#pragma unroll
        for (int t = 0; t < NT; ++t) {
            float e0 = fmaf(acc[t][0], m2i_r[0], cf_r[0]);
            float e1 = fmaf(acc[t][1], m2i_r[1], cf_r[1]);
            float e2 = fmaf(acc[t][2], m2i_r[2], cf_r[2]);
            float e3 = fmaf(acc[t][3], m2i_r[3], cf_r[3]);
            ms0 += fminf(fsqrt_f(e0 + cjr[t]), hb[0]);
            ms1 += fminf(fsqrt_f(e1 + cjr[t]), hb[1]);
            ms2 += fminf(fsqrt_f(e2 + cjr[t]), hb[2]);
            ms3 += fminf(fsqrt_f(e3 + cjr[t]), hb[3]);
        }
        hsum += fmaf((float)NT, hb[0], -ms0);
        hsum += fmaf((float)NT, hb[1], -ms1);
        hsum += fmaf((float)NT, hb[2], -ms2);
        hsum += fmaf((float)NT, hb[3], -ms3);
    }

    // wave reduce + 1 barrier + 1 atomic per block
#pragma unroll
    for (int off = 32; off > 0; off >>= 1) hsum += __shfl_xor(hsum, off);
    if (lane == 0) red[w] = hsum;
    __syncthreads();
    if (threadIdx.x == 0)
        atomicAdd(out, (red[0] + red[1] + red[2] + red[3]) * scale);
}

extern "C" void kernel_launch(void* const* d_in, const int* in_sizes, int n_in,
                              void* d_out, int out_size, void* d_ws, size_t ws_size,
                              hipStream_t stream) {
    const float* feat   = (const float*)d_in[0];
    const float* prot   = (const float*)d_in[1];
    const int*   labels = (const int*)d_in[2];
    float* out = (float*)d_out;
    int Bn = in_sizes[0] / DD;

    bf16x8* pnb = (bf16x8*)d_ws;                       // 28*64*16B = 28672 B
    float* cjw  = (float*)((char*)d_ws + 28 * 64 * 16);

    prep_kernel<<<NPAD, 64, 0, stream>>>(prot, cjw, pnb, out);

    int blocks = (Bn + BROWS - 1) / BROWS;
    float scale = 1.0f / ((float)Bn * (float)(CC - 1));
    if (Bn % BROWS == 0)
        proto_main_kernel<false><<<blocks, 256, 0, stream>>>(feat, pnb, cjw, labels, out, Bn, scale);
    else
        proto_main_kernel<true><<<blocks, 256, 0, stream>>>(feat, pnb, cjw, labels, out, Bn, scale);
}

// Round 12
// 38.300 us; speedup vs baseline: 1.2555x; 1.0541x over previous
//
#include <hip/hip_runtime.h>
#include <hip/hip_bf16.h>
#include <math.h>

#define DD 128
#define CC 100
#define NPAD 112          // 7 tiles of 16
#define NT 7
#define MARGIN_F 0.5f
#define EPS_F 1e-6f
#define RW 16             // rows per wave per chunk
#define CH 8              // chunks per wave (software pipeline depth)
#define BROWS 512         // rows per block = 4 waves * RW * CH -> 512 blocks = 2/CU exact
#define NFRAG (NT * 4)    // 28 B-fragments

typedef __attribute__((ext_vector_type(8))) short bf16x8;
typedef __attribute__((ext_vector_type(4))) float f32x4;

__device__ __forceinline__ float fsqrt_f(float x) { return __builtin_amdgcn_sqrtf(x); }
__device__ __forceinline__ float frcp_f(float x)  { return __builtin_amdgcn_rcpf(x); }

__device__ __forceinline__ short f2bf(float x) {
    __hip_bfloat16 h = __float2bfloat16(x);
    return *reinterpret_cast<short*>(&h);
}

// prep: block j normalizes prototype j, emits cj[j] and B-fragment-major
// bf16 slices. j>=100: zero frags, cj=1e9 (pad kills hinge via min-trick).
// Block 0 initializes out to -MARGIN/(C-1): the label column of the main
// MFMA contributes exactly MARGIN per row (the d_pos gather-MFMA is
// bitwise-identical to it), so one global subtraction compensates exactly.
__global__ void prep_kernel(const float* __restrict__ p,
                            float* __restrict__ cj,
                            bf16x8* __restrict__ pnb,
                            float* __restrict__ out) {
    int j = blockIdx.x, tid = threadIdx.x;
    if (j == 0 && tid == 0) out[0] = -MARGIN_F / (float)(CC - 1);

    float inv = 0.0f;
    if (j < CC) {
        float a = p[j * DD + tid];
        float b = p[j * DD + tid + 64];
        float ss = a * a + b * b;
        float s1 = a + b;
#pragma unroll
        for (int off = 1; off < 64; off <<= 1) {
            ss += __shfl_xor(ss, off);
            s1 += __shfl_xor(s1, off);
        }
        inv = 1.0f / fmaxf(sqrtf(ss), 1e-12f);
        if (tid == 0) cj[j] = ss * inv * inv - 2.0f * EPS_F * (s1 * inv);
    } else {
        if (tid == 0) cj[j] = 1e9f;
    }

    if (tid < 16) {
        int kk = tid >> 2, g = tid & 3;
        int frag = (j >> 4) * 4 + kk;
        int lane = g * 16 + (j & 15);
        bf16x8 o;
        if (j < CC) {
            const float* row = p + j * DD + kk * 32 + g * 8;
#pragma unroll
            for (int q = 0; q < 8; ++q) o[q] = f2bf(row[q] * inv);
        } else {
#pragma unroll
            for (int q = 0; q < 8; ++q) o[q] = 0;
        }
        pnb[frag * 64 + lane] = o;
    }
}

// main: 4 waves/block, 16 rows/wave/chunk, 8 chunks software-pipelined.
// BROWS=512 -> grid 512 = exactly 2 blocks/CU for any VGPR <= 256: no
// residency tail, half the per-block fixed costs (staging, prologue drain,
// reduce/atomic) vs BROWS=256.
// vmcnt carries ONLY the 9 prefetch loads per chunk in the loop; B
// fragments live in LDS (lgkmcnt domain). NO s_setprio (R10: -1.8us with
// 4 symmetric waves -- m190 mechanism).
// TAIL=false (Bn % BROWS == 0): no row clamps or valid masks.
// d_pos via 4-MFMA gather (bitwise-equal to the label column); hinge via
// min-trick: sum relu(hb-dist) = 7*hb - sum min(dist, hb) per lane; pad
// cols (cj=1e9 -> dist~3e4 -> min=hb) contribute exactly 0.
template <bool TAIL>
__global__ __launch_bounds__(256) void proto_main_kernel(
        const float* __restrict__ feat,
        const bf16x8* __restrict__ pnb,
        const float* __restrict__ cj,
        const int* __restrict__ labels,
        float* __restrict__ out,
        int Bn, float scale) {
    const int lane = threadIdx.x & 63;
    const int w = threadIdx.x >> 6;
    const int g = lane >> 4, m = lane & 15;
    const long blkbase = (long)blockIdx.x * BROWS;

    __shared__ bf16x8 pnl[NFRAG * 64];   // 28 KB
    __shared__ float cjs[NPAD];          // 448 B
    __shared__ float red[4];

    // loop-invariant: my 7 columns' cj
    float cjr[NT];
#pragma unroll
    for (int t = 0; t < NT; ++t) cjr[t] = cj[t * 16 + m];

    // issue chunk-0 feature+label loads FIRST (oldest on vmcnt; they land
    // under the LDS staging below)
    float4 va[8];
    int lab;
    {
        long row = blkbase + w * RW + m;
        long rs = (!TAIL || row < Bn) ? row : (long)(Bn - 1);
        lab = labels[rs];
        const float4* fp = (const float4*)(feat + rs * DD);
#pragma unroll
        for (int kk = 0; kk < 4; ++kk) {
            va[kk * 2]     = fp[kk * 8 + g * 2];
            va[kk * 2 + 1] = fp[kk * 8 + g * 2 + 1];
        }
    }

    // stage B fragments + cj table into LDS (once per block)
#pragma unroll
    for (int i = 0; i < NFRAG * 64 / 256; ++i)
        pnl[i * 256 + threadIdx.x] = pnb[i * 256 + threadIdx.x];
    if (threadIdx.x < NPAD) cjs[threadIdx.x] = cj[threadIdx.x];
    __syncthreads();   // drains staging (and chunk-0 loads with it)

    float hsum = 0.f;

#pragma unroll 1
    for (int c = 0; c < CH; ++c) {
        int labc = lab;

        // row-stat sums from raw floats (uses va of chunk c)
        float ss = 0.f, s1 = 0.f;
#pragma unroll
        for (int q = 0; q < 8; ++q) {
            float4 v = va[q];
            ss += v.x * v.x + v.y * v.y + v.z * v.z + v.w * v.w;
            s1 += v.x + v.y + v.z + v.w;
        }

        // raw floats -> bf16 A fragments (frees va for the prefetch)
        bf16x8 afr[4];
#pragma unroll
        for (int kk = 0; kk < 4; ++kk) {
            float4 a = va[kk * 2], b = va[kk * 2 + 1];
            union { bf16x8 v; __hip_bfloat162 h[4]; } u;
            u.h[0] = __float22bfloat162_rn(make_float2(a.x, a.y));
            u.h[1] = __float22bfloat162_rn(make_float2(a.z, a.w));
            u.h[2] = __float22bfloat162_rn(make_float2(b.x, b.y));
            u.h[3] = __float22bfloat162_rn(make_float2(b.z, b.w));
            afr[kk] = u.v;
        }

        // prefetch next chunk's label + features ASAP (ONLY vmcnt ops in
        // the loop; issued before the shuffle/sqrt chain to lengthen the
        // latency shadow)
        if (c + 1 < CH) {
            long nrow = blkbase + (c + 1) * 64 + w * RW + m;
            long nrs = (!TAIL || nrow < Bn) ? nrow : (long)(Bn - 1);
            lab = labels[nrs];
            const float4* fp = (const float4*)(feat + nrs * DD);
#pragma unroll
            for (int kk = 0; kk < 4; ++kk) {
                va[kk * 2]     = fp[kk * 8 + g * 2];
                va[kk * 2 + 1] = fp[kk * 8 + g * 2 + 1];
            }
        }

        // finish row stats (register/LDS-only from here to end of chunk)
        ss += __shfl_xor(ss, 16); ss += __shfl_xor(ss, 32);
        s1 += __shfl_xor(s1, 16); s1 += __shfl_xor(s1, 32);
        float inv = frcp_f(fmaxf(fsqrt_f(ss), 1e-12f));
        float cf = ss * inv * inv + 2.f * EPS_F * (s1 * inv)
                 + (float)DD * (EPS_F * EPS_F);
        float m2i = -2.f * inv;

        // per-row stats for my output rows q=g*4+r (held by lane q)
        float cf_r[4], m2i_r[4];
        int lab_r[4];
#pragma unroll
        for (int r = 0; r < 4; ++r) {
            int addr = (g * 4 + r) << 2;
            cf_r[r]  = __int_as_float(__builtin_amdgcn_ds_bpermute(addr, __float_as_int(cf)));
            m2i_r[r] = __int_as_float(__builtin_amdgcn_ds_bpermute(addr, __float_as_int(m2i)));
            lab_r[r] = __builtin_amdgcn_ds_bpermute(addr, labc);
        }
        // cj of each row's label prototype
        float cjl_r[4];
#pragma unroll
        for (int r = 0; r < 4; ++r) cjl_r[r] = cjs[lab_r[r]];

        // d_pos dots via gathered-B MFMA: col q of B = proto label[row q]
        f32x4 accpos = (f32x4)0.f;
        {
            int lanehi = lane & 48;
            int fbase = (labc >> 4) << 2;
            int lsub  = lanehi + (labc & 15);
#pragma unroll
            for (int kk = 0; kk < 4; ++kk) {
                bf16x8 bp = pnl[(fbase + kk) * 64 + lsub];
                accpos = __builtin_amdgcn_mfma_f32_16x16x32_bf16(
                    afr[kk], bp, accpos, 0, 0, 0);
            }
        }
        // diagonal D[q][q]: holder lane = (q>>2)*16+q holds it in reg q&3
        float a01 = (lane & 1) ? accpos[1] : accpos[0];
        float a23 = (lane & 1) ? accpos[3] : accpos[2];
        float vsrc = (lane & 2) ? a23 : a01;
        float hb[4];
        {
            int hl = (lane >> 4) * 20;   // holder lane for q=g*4+r is 20g+r
#pragma unroll
            for (int r = 0; r < 4; ++r) {
                float dotp = __int_as_float(
                    __builtin_amdgcn_ds_bpermute((hl + r) << 2, __float_as_int(vsrc)));
                float d2p = fmaf(dotp, m2i_r[r], cf_r[r]) + cjl_r[r];
                float dpd = fsqrt_f(fmaxf(d2p, 1e-12f));
                if (TAIL) {
                    long rr = blkbase + c * 64 + w * RW + g * 4 + r;
                    hb[r] = (rr < (long)Bn) ? (dpd + MARGIN_F) : 0.f;
                } else {
                    hb[r] = dpd + MARGIN_F;
                }
            }
        }

        // main MFMA: [16 rows] x [112 cols]; B operands via ds_read_b128
        f32x4 acc[NT];
#pragma unroll
        for (int t = 0; t < NT; ++t) acc[t] = (f32x4)0.f;
#pragma unroll
        for (int t = 0; t < NT; ++t) {
            bf16x8 bfr[4];
#pragma unroll
            for (int kk = 0; kk < 4; ++kk) bfr[kk] = pnl[(t * 4 + kk) * 64 + lane];
#pragma unroll
            for (int kk = 0; kk < 4; ++kk)
                acc[t] = __builtin_amdgcn_mfma_f32_16x16x32_bf16(
                    afr[kk], bfr[kk], acc[t], 0, 0, 0);
        }

        // epilogue: 5 instr/elem {fma, add, sqrt, min, add}
        float ms0 = 0.f, ms1 = 0.f, ms2 = 0.f, ms3 = 0.f;
#pragma unroll
        for (int t = 0; t < NT; ++t) {
            float e0 = fmaf(acc[t][0], m2i_r[0], cf_r[0]);
            float e1 = fmaf(acc[t][1], m2i_r[1], cf_r[1]);
            float e2 = fmaf(acc[t][2], m2i_r[2], cf_r[2]);
            float e3 = fmaf(acc[t][3], m2i_r[3], cf_r[3]);
            ms0 += fminf(fsqrt_f(e0 + cjr[t]), hb[0]);
            ms1 += fminf(fsqrt_f(e1 + cjr[t]), hb[1]);
            ms2 += fminf(fsqrt_f(e2 + cjr[t]), hb[2]);
            ms3 += fminf(fsqrt_f(e3 + cjr[t]), hb[3]);
        }
        hsum += fmaf((float)NT, hb[0], -ms0);
        hsum += fmaf((float)NT, hb[1], -ms1);
        hsum += fmaf((float)NT, hb[2], -ms2);
        hsum += fmaf((float)NT, hb[3], -ms3);
    }

    // wave reduce + 1 barrier + 1 atomic per block
#pragma unroll
    for (int off = 32; off > 0; off >>= 1) hsum += __shfl_xor(hsum, off);
    if (lane == 0) red[w] = hsum;
    __syncthreads();
    if (threadIdx.x == 0)
        atomicAdd(out, (red[0] + red[1] + red[2] + red[3]) * scale);
}

extern "C" void kernel_launch(void* const* d_in, const int* in_sizes, int n_in,
                              void* d_out, int out_size, void* d_ws, size_t ws_size,
                              hipStream_t stream) {
    const float* feat   = (const float*)d_in[0];
    const float* prot   = (const float*)d_in[1];
    const int*   labels = (const int*)d_in[2];
    float* out = (float*)d_out;
    int Bn = in_sizes[0] / DD;

    bf16x8* pnb = (bf16x8*)d_ws;                       // 28*64*16B = 28672 B
    float* cjw  = (float*)((char*)d_ws + 28 * 64 * 16);

    prep_kernel<<<NPAD, 64, 0, stream>>>(prot, cjw, pnb, out);

    int blocks = (Bn + BROWS - 1) / BROWS;
    float scale = 1.0f / ((float)Bn * (float)(CC - 1));
    if (Bn % BROWS == 0)
        proto_main_kernel<false><<<blocks, 256, 0, stream>>>(feat, pnb, cjw, labels, out, Bn, scale);
    else
        proto_main_kernel<true><<<blocks, 256, 0, stream>>>(feat, pnb, cjw, labels, out, Bn, scale);
}